// Round 9
// baseline (459.546 us; speedup 1.0000x reference)
//
#include <hip/hip_runtime.h>

// ---------------- problem constants ----------------
constexpr int cB  = 2;
constexpr int cNR = 16384;
constexpr int cNP = 65536;
constexpr int cE  = 262144;
constexpr int cF  = 128;
constexpr int cEB = cE / 64;   // edge blocks per batch (4096)
constexpr int SP  = 136;   // bf16 row stride in LDS (2-way bank aliasing = free)
constexpr int EFP = 40;    // padded edge-feature row stride (K=4 -> 32 pad)

typedef unsigned short u16;
using f32x4 = __attribute__((ext_vector_type(4))) float;
using s8v   = __attribute__((ext_vector_type(8))) short;

// swizzled-weight segment bases (units of k8 = 8 K-rows; one k8 = 1024 u16)
constexpr int G8_We2 = 0, G8_Wu1 = 16, G8_Wu2 = 64, G8_Wp1 = 80, G8_Wp2 = 112, G8_Wo1 = 128;
constexpr int G8_TOT = 144;
// after main: Wo2 (K=128, N=16-padded): 256 uint4 ; We1 (K=32-padded): 512 uint4
constexpr int SWZ_N = G8_TOT * 128 + 256 + 512;      // uint4 elements (threads)
constexpr int WB_WE1 = (G8_TOT * 128 + 256) * 8;     // u16 offset of We1 block

// ws layout (float offsets)
constexpr size_t WS_CNT  = 0;
constexpr size_t WS_POS  = WS_CNT + (size_t)cB * cNP;
constexpr size_t WS_BSUM = WS_POS + (size_t)cB * cNP;
constexpr size_t WS_SS   = WS_BSUM + 512;
constexpr size_t WS_WB   = WS_SS + 3 * cB * 256;
constexpr size_t WS_RB   = WS_WB + (size_t)SWZ_N * 4;
constexpr size_t WS_PB   = WS_RB + (size_t)cB * cNR * cF / 2;
constexpr size_t WS_EL   = WS_PB + (size_t)cB * cNP * cF / 2;
constexpr size_t WS_EB   = WS_EL + (size_t)cB * cE;

// prep fusion block partition
constexpr int PB_SWZ  = (SWZ_N + 255) / 256;                       // 75
constexpr int PB_ZERO = (int)((size_t)cB * cNP * 4 / 16 / 256);    // 128
constexpr int PB_COND = 3 * cB;                                    // 6
constexpr int N2A = (int)((size_t)cB * cNR * cF / 2);              // rnode u32 pairs
constexpr int N2B = (int)((size_t)cB * cNP * cF / 2);              // pnode u32 pairs
constexpr int PB_CVT  = (N2A + N2B + 255) / 256;                   // 40960
constexpr int PB_TOT  = PB_SWZ + PB_ZERO + PB_COND + PB_CVT;

// ---------------- helpers ----------------
__device__ __forceinline__ float bf2f(u16 u) {
  union { unsigned int i; float f; } v; v.i = ((unsigned int)u) << 16; return v.f;
}
__device__ __forceinline__ u16 f2bf(float f) {        // RNE (weights only)
  union { float f; unsigned int i; } v; v.f = f;
  unsigned int x = v.i;
  return (u16)((x + 0x7fffu + ((x >> 16) & 1u)) >> 16);
}
// fast round-half-up bf16 (intermediates; 2 VALU ops)
__device__ __forceinline__ u16 f2bf_fast(float f) {
  return (u16)((__float_as_uint(f) + 0x8000u) >> 16);
}
// packed pair via v_perm_b32 (3 VALU ops total): low=bf16(a), high=bf16(b)
__device__ __forceinline__ unsigned pack2(float a, float b) {
  return __builtin_amdgcn_perm(__float_as_uint(b) + 0x8000u,
                               __float_as_uint(a) + 0x8000u, 0x07060302u);
}
// swish via single v_rcp_f32 (1-ulp)
__device__ __forceinline__ float swishf(float x) {
  return x * __builtin_amdgcn_rcpf(1.0f + __expf(-x));
}

// DPP add: x += dpp<CTRL>(x). Pure VALU (no LGKM). CTRL must be constexpr.
template <int CTRL>
__device__ __forceinline__ float dpp_add(float x) {
  int xi = __float_as_int(x);
  int r = __builtin_amdgcn_update_dpp(xi, xi, CTRL, 0xf, 0xf, false);
  return x + __int_as_float(r);
}

// direct global->LDS DMA: 4B per lane, dest = uniform base + lane*4
__device__ __forceinline__ void gload4_lds(const u16* gsrc, u16* lds) {
  __builtin_amdgcn_global_load_lds(
      (const __attribute__((address_space(1))) void*)gsrc,
      (__attribute__((address_space(3))) void*)lds, 4, 0, 0);
}

// ---- column-strip MFMA pass, M=64: wave covers rows 0..63 x 32-col strip ----
// (setprio removed: measured null on dur and correlated with +24MB partial-line
//  write amplification on the ebuf tail in r8)
__device__ __forceinline__ void kloop128s(const u16* act, const u16* __restrict__ wbg,
                                          f32x4 (&acc)[4][2], int cw, int l16, int quad) {
  s8v bf[4][2];
#pragma unroll
  for (int k0 = 0; k0 < 4; ++k0)
#pragma unroll
    for (int ci = 0; ci < 2; ++ci)
      bf[k0][ci] = *(const s8v*)(wbg + ((size_t)(k0 * 4 + quad) * 128 + cw + ci * 16 + l16) * 8);
#pragma unroll
  for (int k0 = 0; k0 < 4; ++k0) {
    s8v af[4];
#pragma unroll
    for (int ri = 0; ri < 4; ++ri)
      af[ri] = *(const s8v*)(act + (ri * 16 + l16) * SP + k0 * 32 + quad * 8);
#pragma unroll
    for (int ri = 0; ri < 4; ++ri)
#pragma unroll
      for (int ci = 0; ci < 2; ++ci)
        acc[ri][ci] = __builtin_amdgcn_mfma_f32_16x16x32_bf16(af[ri], bf[k0][ci], acc[ri][ci], 0, 0, 0);
  }
}

// ---- M=32 variant for pnode (rows 0..31) ----
__device__ __forceinline__ void kloop128h(const u16* act, const u16* __restrict__ wbg,
                                          f32x4 (&acc)[2][2], int cw, int l16, int quad) {
  s8v bf[4][2];
#pragma unroll
  for (int k0 = 0; k0 < 4; ++k0)
#pragma unroll
    for (int ci = 0; ci < 2; ++ci)
      bf[k0][ci] = *(const s8v*)(wbg + ((size_t)(k0 * 4 + quad) * 128 + cw + ci * 16 + l16) * 8);
#pragma unroll
  for (int k0 = 0; k0 < 4; ++k0) {
    s8v af[2];
#pragma unroll
    for (int ri = 0; ri < 2; ++ri)
      af[ri] = *(const s8v*)(act + (ri * 16 + l16) * SP + k0 * 32 + quad * 8);
#pragma unroll
    for (int ri = 0; ri < 2; ++ri)
#pragma unroll
      for (int ci = 0; ci < 2; ++ci)
        acc[ri][ci] = __builtin_amdgcn_mfma_f32_16x16x32_bf16(af[ri], bf[k0][ci], acc[ri][ci], 0, 0, 0);
  }
}

__device__ __forceinline__ void init_acc_s(f32x4 (&acc)[4][2], const float* __restrict__ bias,
                                           int cw, int l16) {
#pragma unroll
  for (int ci = 0; ci < 2; ++ci) {
    float bv = bias[cw + ci * 16 + l16];
#pragma unroll
    for (int ri = 0; ri < 4; ++ri) acc[ri][ci] = (f32x4){bv, bv, bv, bv};
  }
}

__device__ __forceinline__ void init_acc_h(f32x4 (&acc)[2][2], const float* __restrict__ bias,
                                           int cw, int l16) {
#pragma unroll
  for (int ci = 0; ci < 2; ++ci) {
    float bv = bias[cw + ci * 16 + l16];
#pragma unroll
    for (int ri = 0; ri < 2; ++ri) acc[ri][ci] = (f32x4){bv, bv, bv, bv};
  }
}

// conditioned LayerNorm, M=64 rows; 16-lane reduce via DPP row_ror (VALU only)
__device__ __forceinline__ void cond_norm_s(f32x4 (&acc)[4][2], float* red, float* musig,
                                            const float* __restrict__ ssp,
                                            int cw, int l16, int quad, int wv, int t) {
  __syncthreads();                 // prior LDS reads done; red/musig reuse safe
#pragma unroll
  for (int ri = 0; ri < 4; ++ri)
#pragma unroll
    for (int reg = 0; reg < 4; ++reg) {
      float v0 = acc[ri][0][reg], v1 = acc[ri][1][reg];
      float s = v0 + v1;
      float q = v0 * v0 + v1 * v1;
      s = dpp_add<0x128>(s); q = dpp_add<0x128>(q);   // row_ror:8
      s = dpp_add<0x124>(s); q = dpp_add<0x124>(q);   // row_ror:4
      s = dpp_add<0x122>(s); q = dpp_add<0x122>(q);   // row_ror:2
      s = dpp_add<0x121>(s); q = dpp_add<0x121>(q);   // row_ror:1
      if (l16 == 0) {
        int row = ri * 16 + quad * 4 + reg;
        red[row * 8 + wv * 2]     = s;
        red[row * 8 + wv * 2 + 1] = q;
      }
    }
  __syncthreads();
  if (t < 64) {
    float sum = red[t * 8 + 0] + red[t * 8 + 2] + red[t * 8 + 4] + red[t * 8 + 6];
    float sq  = red[t * 8 + 1] + red[t * 8 + 3] + red[t * 8 + 5] + red[t * 8 + 7];
    float mu  = sum * (1.0f / 128.0f);
    float var = fmaxf(sq * (1.0f / 128.0f) - mu * mu, 0.0f);
    musig[t * 2]     = mu;
    musig[t * 2 + 1] = __builtin_amdgcn_rsqf(var + 1e-6f);
  }
  __syncthreads();
  float scl[2], shf[2];
#pragma unroll
  for (int ci = 0; ci < 2; ++ci) {
    int col = cw + ci * 16 + l16;
    scl[ci] = 1.0f + ssp[col];
    shf[ci] = ssp[128 + col];
  }
#pragma unroll
  for (int ri = 0; ri < 4; ++ri)
#pragma unroll
    for (int reg = 0; reg < 4; ++reg) {
      int row = ri * 16 + quad * 4 + reg;
      float mu = musig[row * 2], is = musig[row * 2 + 1];
#pragma unroll
      for (int ci = 0; ci < 2; ++ci)
        acc[ri][ci][reg] = (acc[ri][ci][reg] - mu) * is * scl[ci] + shf[ci];
    }
}

// conditioned LayerNorm, M=32 rows
__device__ __forceinline__ void cond_norm_h(f32x4 (&acc)[2][2], float* red, float* musig,
                                            const float* __restrict__ ssp,
                                            int cw, int l16, int quad, int wv, int t) {
  __syncthreads();
#pragma unroll
  for (int ri = 0; ri < 2; ++ri)
#pragma unroll
    for (int reg = 0; reg < 4; ++reg) {
      float v0 = acc[ri][0][reg], v1 = acc[ri][1][reg];
      float s = v0 + v1;
      float q = v0 * v0 + v1 * v1;
      s = dpp_add<0x128>(s); q = dpp_add<0x128>(q);
      s = dpp_add<0x124>(s); q = dpp_add<0x124>(q);
      s = dpp_add<0x122>(s); q = dpp_add<0x122>(q);
      s = dpp_add<0x121>(s); q = dpp_add<0x121>(q);
      if (l16 == 0) {
        int row = ri * 16 + quad * 4 + reg;
        red[row * 8 + wv * 2]     = s;
        red[row * 8 + wv * 2 + 1] = q;
      }
    }
  __syncthreads();
  if (t < 32) {
    float sum = red[t * 8 + 0] + red[t * 8 + 2] + red[t * 8 + 4] + red[t * 8 + 6];
    float sq  = red[t * 8 + 1] + red[t * 8 + 3] + red[t * 8 + 5] + red[t * 8 + 7];
    float mu  = sum * (1.0f / 128.0f);
    float var = fmaxf(sq * (1.0f / 128.0f) - mu * mu, 0.0f);
    musig[t * 2]     = mu;
    musig[t * 2 + 1] = __builtin_amdgcn_rsqf(var + 1e-6f);
  }
  __syncthreads();
  float scl[2], shf[2];
#pragma unroll
  for (int ci = 0; ci < 2; ++ci) {
    int col = cw + ci * 16 + l16;
    scl[ci] = 1.0f + ssp[col];
    shf[ci] = ssp[128 + col];
  }
#pragma unroll
  for (int ri = 0; ri < 2; ++ri)
#pragma unroll
    for (int reg = 0; reg < 4; ++reg) {
      int row = ri * 16 + quad * 4 + reg;
      float mu = musig[row * 2], is = musig[row * 2 + 1];
#pragma unroll
      for (int ci = 0; ci < 2; ++ci)
        acc[ri][ci][reg] = (acc[ri][ci][reg] - mu) * is * scl[ci] + shf[ci];
    }
}

template <bool DOSWISH>
__device__ __forceinline__ void store_s(u16* buf, const f32x4 (&acc)[4][2],
                                        int cw, int l16, int quad) {
#pragma unroll
  for (int ri = 0; ri < 4; ++ri)
#pragma unroll
    for (int reg = 0; reg < 4; ++reg) {
      int row = ri * 16 + quad * 4 + reg;
#pragma unroll
      for (int ci = 0; ci < 2; ++ci) {
        float v = acc[ri][ci][reg];
        if (DOSWISH) v = swishf(v);
        buf[row * SP + cw + ci * 16 + l16] = f2bf_fast(v);
      }
    }
}

template <bool DOSWISH>
__device__ __forceinline__ void store_h(u16* buf, const f32x4 (&acc)[2][2],
                                        int cw, int l16, int quad) {
#pragma unroll
  for (int ri = 0; ri < 2; ++ri)
#pragma unroll
    for (int reg = 0; reg < 4; ++reg) {
      int row = ri * 16 + quad * 4 + reg;
#pragma unroll
      for (int ci = 0; ci < 2; ++ci) {
        float v = acc[ri][ci][reg];
        if (DOSWISH) v = swishf(v);
        buf[row * SP + cw + ci * 16 + l16] = f2bf_fast(v);
      }
    }
}

// ---------------- fused prep kernel: swz | zero(cntI) | cond | cvt ----------------
struct SwzSrc { const float* p[7]; };  // We2, Wu1, Wu2, Wp1, Wp2, Wo1, We1

struct PrepArgs {
  SwzSrc sw; const float* Wo2; u16* wb;
  const float* rnode; u16* rnb;
  const float* pnode; u16* pnb;
  const float* tau;
  const float* C1[3]; const float* c1v[3]; const float* C2[3]; const float* c2v[3];
  float* ss;
  float4* cnt4;
};

__device__ void swz_one(int t, const SwzSrc& s, const float* __restrict__ Wo2,
                        u16* __restrict__ wb) {
  if (t >= SWZ_N) return;
  if (t >= G8_TOT * 128 + 256) {          // We1: K=4 zero-padded to 32
    int idx3 = t - (G8_TOT * 128 + 256);
    int k8 = idx3 >> 7, n = idx3 & 127;
    const float* We1 = s.p[6];
    u16 v[8];
#pragma unroll
    for (int j = 0; j < 8; ++j) {
      int k = k8 * 8 + j;
      v[j] = (k < 4) ? f2bf(We1[(size_t)k * 128 + n]) : (u16)0;
    }
    ((uint4*)wb)[t] = *(uint4*)v;
    return;
  }
  if (t >= G8_TOT * 128) {                // Wo2 tail
    int idx2 = t - G8_TOT * 128;
    int k8 = idx2 >> 4, n = idx2 & 15;
    u16 v[8];
#pragma unroll
    for (int j = 0; j < 8; ++j)
      v[j] = (n < 4) ? f2bf(Wo2[(size_t)(k8 * 8 + j) * 4 + n]) : (u16)0;
    ((uint4*)wb)[G8_TOT * 128 + k8 * 16 + n] = *(uint4*)v;
    return;
  }
  int n = t & 127, g8 = t >> 7;
  int seg, base;
  if (g8 < G8_Wu1)      { seg = 0; base = G8_We2; }
  else if (g8 < G8_Wu2) { seg = 1; base = G8_Wu1; }
  else if (g8 < G8_Wp1) { seg = 2; base = G8_Wu2; }
  else if (g8 < G8_Wp2) { seg = 3; base = G8_Wp1; }
  else if (g8 < G8_Wo1) { seg = 4; base = G8_Wp2; }
  else                  { seg = 5; base = G8_Wo1; }
  const float* W = s.p[seg];
  int k8l = g8 - base;
  u16 v[8];
#pragma unroll
  for (int j = 0; j < 8; ++j) {
    int kd = k8l * 8 + j;
    int ks = kd;
    if (seg == 3 && kd >= 128) {          // Wp1 mean half: inverse col-interleave
      int p = kd - 128;
      ks = 128 + ((p >> 5) << 5) + ((p & 1) << 4) + ((p & 31) >> 1);
    }
    v[j] = f2bf(W[(size_t)ks * 128 + n]);
  }
  ((uint4*)wb)[g8 * 128 + n] = *(uint4*)v;
}

__global__ void prep_kernel(PrepArgs a) {
  int blk = blockIdx.x, tid = threadIdx.x;
  if (blk < PB_SWZ) {
    swz_one(blk * 256 + tid, a.sw, a.Wo2, a.wb);
    return;
  }
  blk -= PB_SWZ;
  if (blk < PB_ZERO) {
    a.cnt4[blk * 256 + tid] = make_float4(0.f, 0.f, 0.f, 0.f);
    return;
  }
  blk -= PB_ZERO;
  if (blk < PB_COND) {
    int set = blk / cB, b = blk - set * cB, j = tid;
    const float* C1 = a.C1[set];  const float* c1 = a.c1v[set];
    const float* C2 = a.C2[set];  const float* c2 = a.c2v[set];
    float tf = a.tau[b];
    float acc = c2[j];
    for (int k = 0; k < 16; ++k) {
      float h = swishf(tf * C1[k] + c1[k]);
      acc = fmaf(h, C2[k * 256 + j], acc);
    }
    a.ss[(size_t)set * cB * 256 + (size_t)b * 256 + j] = acc;
    return;
  }
  blk -= PB_COND;
  int i = blk * 256 + tid;
  if (i < N2A) {
    float2 v = ((const float2*)a.rnode)[i];
    ((unsigned*)a.rnb)[i] = pack2(v.x, v.y);
  } else if (i < N2A + N2B) {
    int k = i - N2A;
    float2 v = ((const float2*)a.pnode)[k];
    ((unsigned*)a.pnb)[k] = pack2(v.x, v.y);
  }
}

// ---------------- CSR build: histogram -> scan -> fill ----------------
__global__ void hist_kernel(const int* __restrict__ receivers, int* __restrict__ cntI) {
  int i = blockIdx.x * 256 + threadIdx.x;
  if (i >= cB * cE) return;
  int b = i / cE;
  int r = min(max(receivers[i], 0), cNP - 1);
  atomicAdd(&cntI[(size_t)b * cNP + r], 1);
}

__global__ void scanA_kernel(const int* __restrict__ cntI, int* __restrict__ bsum) {
  __shared__ int red[256];
  int g = blockIdx.x, t = threadIdx.x;
  red[t] = cntI[g * 256 + t];
  __syncthreads();
  for (int s = 128; s > 0; s >>= 1) {
    if (t < s) red[t] += red[t + s];
    __syncthreads();
  }
  if (t == 0) bsum[g] = red[0];
}

__global__ void scanB_kernel(int* __restrict__ bsum) {   // 1 block, 512 threads
  __shared__ int s0[512], s1[512];
  int t = threadIdx.x;
  int v0 = bsum[t];
  s0[t] = v0;
  __syncthreads();
  int* src = s0; int* dst = s1;
  for (int s = 1; s < 512; s <<= 1) {
    dst[t] = src[t] + ((t >= s) ? src[t - s] : 0);
    __syncthreads();
    int* tmp = src; src = dst; dst = tmp;
  }
  bsum[t] = src[t] - v0;   // exclusive block offsets
}

__global__ void scanC_kernel(const int* __restrict__ cntI, const int* __restrict__ bsum,
                             int* __restrict__ pos) {
  __shared__ int s0[256], s1[256];
  int g = blockIdx.x, t = threadIdx.x;
  int v0 = cntI[g * 256 + t];
  s0[t] = v0;
  __syncthreads();
  int* src = s0; int* dst = s1;
  for (int s = 1; s < 256; s <<= 1) {
    dst[t] = src[t] + ((t >= s) ? src[t - s] : 0);
    __syncthreads();
    int* tmp = src; src = dst; dst = tmp;
  }
  pos[g * 256 + t] = src[t] - v0 + bsum[g];   // exclusive global offset
}

__global__ void fill_kernel(const int* __restrict__ receivers, int* __restrict__ pos,
                            int* __restrict__ elist) {
  int i = blockIdx.x * 256 + threadIdx.x;
  if (i >= cB * cE) return;
  int b = i / cE, e = i - b * cE;
  int r = min(max(receivers[i], 0), cNP - 1);
  int idx = atomicAdd(&pos[(size_t)b * cNP + r], 1);
  elist[idx] = e;           // batch0 fills [0,E), batch1 [E,2E); pos ends = row ends
}

// ---------------- fused MFMA edge pipeline (r6 structure, proven best) ----------------
struct EWb { const float *be1, *be2, *bu1, *bu2; };

struct __align__(16) EdgeSmem {
  u16 bufE[64 * SP];            // e_emb (post-norm bf16; Wu1 e-operand + final residual)
  u16 bufX[64 * SP];            // h_embed -> sf -> rf -> h2
  union {
    u16 ef[64 * EFP];           // padded bf16 edge features (embed MFMA A)
    struct { float red[512]; float musig[128]; } r;
  } u;
  int sidx[64], ridx[64];
};  // 40448 B -> 4 blocks/CU

__global__ __launch_bounds__(256, 4) void edge_mfma(
    const u16* __restrict__ rnb, const u16* __restrict__ pnb,
    const float* __restrict__ efeat, const int* __restrict__ senders,
    const int* __restrict__ receivers, const int* __restrict__ elist,
    EWb w, const u16* __restrict__ wb,
    const float* __restrict__ ss, u16* __restrict__ ebuf) {
  __shared__ EdgeSmem sm;
  const int t = threadIdx.x, wv = t >> 6, lane = t & 63, l16 = lane & 15, quad = lane >> 4;
  const int cw = wv * 32;          // column strip base
  // XCD-chunked swizzle: contiguous sorted-edge chunks per XCD (L2 locality on pnb).
  const int raw = blockIdx.x;                       // 0..8191
  const int swz = (raw & 7) * (cB * cEB / 8) + (raw >> 3);
  const int b   = swz / cEB;

  // ---- stage sorted edge ids, indices, zero-padded bf16 edge features ----
  if (t < 64) {
    int eid = elist[(size_t)swz * 64 + t];          // coalesced
    size_t ge = (size_t)b * cE + eid;
    sm.sidx[t] = min(max(senders[ge], 0), cNR - 1);
    sm.ridx[t] = min(max(receivers[ge], 0), cNP - 1);
    float4 ef = *(const float4*)(efeat + ge * 4);   // random 16B gather (L2/L3 resident)
    uint4 w0 = { pack2(ef.x, ef.y), pack2(ef.z, ef.w), 0u, 0u };
    uint4 zz = { 0u, 0u, 0u, 0u };
    uint4* rowp = (uint4*)(sm.u.ef + (size_t)t * EFP);
    rowp[0] = w0; rowp[1] = zz; rowp[2] = zz; rowp[3] = zz; rowp[4] = zz;
  }
  __syncthreads();  // b1

  f32x4 acc[4][2];

  // ---- embed L1 via MFMA (K=32 zero-padded) + swish -> X ----
  init_acc_s(acc, w.be1, cw, l16);
  {
    const u16* wbe1 = wb + WB_WE1;
    s8v bf0 = *(const s8v*)(wbe1 + ((size_t)quad * 128 + cw + l16) * 8);
    s8v bf1 = *(const s8v*)(wbe1 + ((size_t)quad * 128 + cw + 16 + l16) * 8);
#pragma unroll
    for (int ri = 0; ri < 4; ++ri) {
      s8v af = *(const s8v*)(sm.u.ef + (ri * 16 + l16) * EFP + quad * 8);
      acc[ri][0] = __builtin_amdgcn_mfma_f32_16x16x32_bf16(af, bf0, acc[ri][0], 0, 0, 0);
      acc[ri][1] = __builtin_amdgcn_mfma_f32_16x16x32_bf16(af, bf1, acc[ri][1], 0, 0, 0);
    }
  }
  store_s<true>(sm.bufX, acc, cw, l16, quad);   // h_embed
  __syncthreads();  // b2

  // ---- embed L2 + cond-norm(set0) -> e_emb into bufE (LDS) ----
  init_acc_s(acc, w.be2, cw, l16);
  kloop128s(sm.bufX, wb + (size_t)G8_We2 * 1024, acc, cw, l16, quad);
  cond_norm_s(acc, sm.u.r.red, sm.u.r.musig, ss + (size_t)b * 256, cw, l16, quad, wv, t);
  store_s<false>(sm.bufE, acc, cw, l16, quad);  // e_emb

  // ---- update L1 (K=384 = sf|e|rf), sequenced through bufX ----
#pragma unroll
  for (int rr = 0; rr < 16; ++rr) {   // sf: global->LDS DMA; SALU base via readfirstlane
    int row = wv * 16 + rr;
    int si = __builtin_amdgcn_readfirstlane(sm.sidx[row]);
    gload4_lds(rnb + ((size_t)b * cNR + si) * cF + lane * 2,
               sm.bufX + row * SP);
  }
  f32x4 accU[4][2];
  init_acc_s(accU, w.bu1, cw, l16);
  __syncthreads();  // b4: sf landed; bufE(e_emb) visible to all waves
  kloop128s(sm.bufX, wb + (size_t)(G8_Wu1 + 16) * 1024, accU, cw, l16, quad);  // sf block
  __syncthreads();  // b5: sf reads done
#pragma unroll
  for (int rr = 0; rr < 16; ++rr) {   // rf: DMA from bf16 pnode (sorted -> L2-local)
    int row = wv * 16 + rr;
    int ri_ = __builtin_amdgcn_readfirstlane(sm.ridx[row]);
    gload4_lds(pnb + ((size_t)b * cNP + ri_) * cF + lane * 2,
               sm.bufX + row * SP);
  }
  // e block from bufE overlaps the rf DMA flight time
  kloop128s(sm.bufE, wb + (size_t)G8_Wu1 * 1024, accU, cw, l16, quad);         // e block
  __syncthreads();  // b6: rf landed
  kloop128s(sm.bufX, wb + (size_t)(G8_Wu1 + 32) * 1024, accU, cw, l16, quad);  // rf block
  __syncthreads();  // b7: rf reads done
  store_s<true>(sm.bufX, accU, cw, l16, quad);  // h2
  __syncthreads();  // b8

  // ---- update L2 + cond-norm(set1) ----
  init_acc_s(acc, w.bu2, cw, l16);
  kloop128s(sm.bufX, wb + (size_t)G8_Wu2 * 1024, acc, cw, l16, quad);
  cond_norm_s(acc, sm.u.r.red, sm.u.r.musig, ss + (size_t)(cB + b) * 256, cw, l16, quad, wv, t);

  // ---- e_final = e_emb + u -> DIRECT packed store to ebuf (col-interleaved) ----
  // position p = 32*wv + 2*l16 + ci holds feature f = 32*wv + 16*ci + l16;
  // compensated by the Wp1-mean K-permute in swz. No LDS round trip, no barrier.
  {
    unsigned* eb32o = (unsigned*)ebuf + (size_t)(swz * 64) * 64;
#pragma unroll
    for (int ri = 0; ri < 4; ++ri)
#pragma unroll
      for (int reg = 0; reg < 4; ++reg) {
        int row = ri * 16 + quad * 4 + reg;
        float v0 = acc[ri][0][reg] + bf2f(sm.bufE[row * SP + cw + l16]);
        float v1 = acc[ri][1][reg] + bf2f(sm.bufE[row * SP + cw + 16 + l16]);
        eb32o[(size_t)row * 64 + wv * 16 + l16] = pack2(v0, v1);
      }
  }
}

// ---------------- fused MFMA pnode pipeline: 32-node tiles for load balance ----------------
// 4096 blocks (vs 2048): 4 scheduling rounds instead of 2 -> segment-scan-length
// stragglers cost half. M=32 MFMA (acc[2][2]); per-wave scan = 8 nodes.
struct PWb { const float *bp1, *bp2, *bo1, *bo2; };

struct __align__(16) PnodeSmem {
  u16 bufP[32 * SP];   // pf -> p_new
  u16 bufX[32 * SP];   // mean (col-interleaved; Wp1-mean K permuted) -> h1 -> h_out
  float red[256];
  float musig[64];
  float cinv[32];
  int startA[32];
  int endA[40];        // +8 sentinel for wave 3
};  // ~19.0 KB -> 4 blocks/CU (reg bin caps waves anyway)

__global__ __launch_bounds__(256, 4) void pnode_mfma(
    const u16* __restrict__ pnb, PWb w, const u16* __restrict__ wb,
    const float* __restrict__ ss, const unsigned* __restrict__ eb32,
    const int* __restrict__ cntI, const int* __restrict__ pos,
    float* __restrict__ out) {
  __shared__ PnodeSmem sm;
  const int t = threadIdx.x, wv = t >> 6, lane = t & 63, l16 = lane & 15, quad = lane >> 4;
  const int cw = wv * 32;
  const int b  = blockIdx.y;
  const int n0 = blockIdx.x * 32;

  if (t < 32) {
    size_t g = (size_t)b * cNP + n0 + t;
    int c  = cntI[g];
    int e_ = pos[g];               // end offset (post-fill)
    sm.startA[t] = e_ - c;
    sm.endA[t]   = e_;
    sm.cinv[t]   = __builtin_amdgcn_rcpf(fmaxf((float)c, 1.0f));
  } else if (t < 40) {
    sm.endA[t] = 0x7fffffff;       // sentinel
  }
  __syncthreads();  // b1

  // ---- pf rows -> bufP (coalesced) ----
#pragma unroll
  for (int rr = 0; rr < 8; ++rr) {
    int row = wv * 8 + rr;
    unsigned pvu = *(const unsigned*)(pnb + (((size_t)b * cNP + n0 + row) * cF + lane * 2));
    *(unsigned*)(sm.bufP + row * SP + lane * 2) = pvu;
  }

  // ---- segment-mean: linear scan of this wave's 8 nodes' contiguous range ----
  {
    const int nodeLo = wv * 8;
    int cur  = nodeLo;
    int bnd  = __builtin_amdgcn_readfirstlane(sm.endA[cur]);
    int s    = __builtin_amdgcn_readfirstlane(sm.startA[nodeLo]);
    const int sEnd = __builtin_amdgcn_readfirstlane(sm.endA[nodeLo + 7]);
    float a0 = 0.f, a1 = 0.f;
    for (; s < sEnd; s += 8) {
      unsigned v[8];
      int m = sEnd - s;            // >=1
#pragma unroll
      for (int j = 0; j < 8; ++j)
        if (j < m) v[j] = eb32[(size_t)(s + j) * 64 + lane];   // 8-deep MLP, saddr form
#pragma unroll
      for (int j = 0; j < 8; ++j) {
        if (j < m) {
          while (s + j == bnd) {   // flush finished node(s); wave-uniform
            float ci = sm.cinv[cur];
            *(unsigned*)(sm.bufX + cur * SP + lane * 2) = pack2(a0 * ci, a1 * ci);
            a0 = a1 = 0.f; ++cur;
            bnd = __builtin_amdgcn_readfirstlane(sm.endA[cur]);
          }
          a0 += bf2f((u16)(v[j] & 0xffffu));
          a1 += bf2f((u16)(v[j] >> 16));
        }
      }
    }
    while (cur < nodeLo + 8) {     // flush trailing node(s)
      float ci = sm.cinv[cur];
      *(unsigned*)(sm.bufX + cur * SP + lane * 2) = pack2(a0 * ci, a1 * ci);
      a0 = a1 = 0.f; ++cur;
    }
  }
  __syncthreads();  // b2

  f32x4 acc[2][2];

  // ---- pnode L1: K=256 over [pf|mean] (mean half K-permuted in wb) ----
  init_acc_h(acc, w.bp1, cw, l16);
  kloop128h(sm.bufP, wb + (size_t)G8_Wp1 * 1024, acc, cw, l16, quad);
  kloop128h(sm.bufX, wb + (size_t)(G8_Wp1 + 16) * 1024, acc, cw, l16, quad);
  __syncthreads();  // b3: all waves done reading bufX(mean)
  store_h<true>(sm.bufX, acc, cw, l16, quad);  // h1
  __syncthreads();  // b4

  // ---- pnode L2 + cond-norm(set2) + residual -> bufP ----
  init_acc_h(acc, w.bp2, cw, l16);
  kloop128h(sm.bufX, wb + (size_t)G8_Wp2 * 1024, acc, cw, l16, quad);
  cond_norm_h(acc, sm.red, sm.musig, ss + (size_t)(2 * cB + b) * 256, cw, l16, quad, wv, t);
#pragma unroll
  for (int ri = 0; ri < 2; ++ri)
#pragma unroll
    for (int reg = 0; reg < 4; ++reg) {
      int row = ri * 16 + quad * 4 + reg;
#pragma unroll
      for (int ci = 0; ci < 2; ++ci)
        acc[ri][ci][reg] += bf2f(sm.bufP[row * SP + cw + ci * 16 + l16]);
    }
  __syncthreads();  // b5: all waves done residual-reading bufP
  store_h<false>(sm.bufP, acc, cw, l16, quad);  // p_new
  __syncthreads();  // b6

  // ---- output L1: K=128 -> bufX ----
  init_acc_h(acc, w.bo1, cw, l16);
  kloop128h(sm.bufP, wb + (size_t)G8_Wo1 * 1024, acc, cw, l16, quad);
  store_h<true>(sm.bufX, acc, cw, l16, quad);
  __syncthreads();  // b7

  // ---- output L2 via MFMA: K=128, N=16 (4 used); waves 0-1 cover the 32 rows ----
  if (wv < 2) {
    const u16* wo2 = wb + (size_t)G8_TOT * 1024;
    float bv = (l16 < 4) ? w.bo2[l16] : 0.0f;
    f32x4 a1 = {bv, bv, bv, bv};
#pragma unroll
    for (int k0 = 0; k0 < 4; ++k0) {
      s8v af = *(const s8v*)(sm.bufX + (wv * 16 + l16) * SP + k0 * 32 + quad * 8);
      s8v bf = *(const s8v*)(wo2 + ((size_t)(k0 * 4 + quad) * 16 + l16) * 8);
      a1 = __builtin_amdgcn_mfma_f32_16x16x32_bf16(af, bf, a1, 0, 0, 0);
    }
    if (l16 < 4) {
      size_t obase = (size_t)b * cNP + n0 + wv * 16 + quad * 4;
#pragma unroll
      for (int reg = 0; reg < 4; ++reg)
        out[(obase + reg) * 4 + l16] = a1[reg];
    }
  }
}

// ---------------- launch ----------------
extern "C" void kernel_launch(void* const* d_in, const int* in_sizes, int n_in,
                              void* d_out, int out_size, void* d_ws, size_t ws_size,
                              hipStream_t stream) {
  const float* rnode = (const float*)d_in[0];
  const float* pnode = (const float*)d_in[1];
  const float* efeat = (const float*)d_in[2];
  const float* tau   = (const float*)d_in[3];
  const int* senders   = (const int*)d_in[40];
  const int* receivers = (const int*)d_in[41];
  float* ws = (float*)d_ws;
  int* cntI  = (int*)(ws + WS_CNT);
  int* pos   = (int*)(ws + WS_POS);
  int* bsum  = (int*)(ws + WS_BSUM);
  u16* wb    = (u16*)(ws + WS_WB);
  u16* rnb   = (u16*)(ws + WS_RB);         // bf16 rnode copy
  u16* pnb   = (u16*)(ws + WS_PB);         // bf16 pnode copy
  int* elist = (int*)(ws + WS_EL);         // receiver-sorted edge ids [B*E]
  u16* ebuf  = (u16*)(ws + WS_EB);         // sorted edge latents [B*E][128]

  PrepArgs pa;
  pa.sw.p[0] = (const float*)d_in[5];   // We2
  pa.sw.p[1] = (const float*)d_in[12];  // Wu1
  pa.sw.p[2] = (const float*)d_in[13];  // Wu2
  pa.sw.p[3] = (const float*)d_in[20];  // Wp1
  pa.sw.p[4] = (const float*)d_in[21];  // Wp2
  pa.sw.p[5] = (const float*)d_in[36];  // Wo1
  pa.sw.p[6] = (const float*)d_in[4];   // We1 (K=4 -> 32 padded)
  pa.Wo2 = (const float*)d_in[37];
  pa.wb = wb;
  pa.rnode = rnode; pa.rnb = rnb;
  pa.pnode = pnode; pa.pnb = pnb;
  pa.tau = tau;
  pa.C1[0] = (const float*)d_in[8];   pa.c1v[0] = (const float*)d_in[10];
  pa.C2[0] = (const float*)d_in[9];   pa.c2v[0] = (const float*)d_in[11];
  pa.C1[1] = (const float*)d_in[16];  pa.c1v[1] = (const float*)d_in[18];
  pa.C2[1] = (const float*)d_in[17];  pa.c2v[1] = (const float*)d_in[19];
  pa.C1[2] = (const float*)d_in[24];  pa.c1v[2] = (const float*)d_in[26];
  pa.C2[2] = (const float*)d_in[25];  pa.c2v[2] = (const float*)d_in[27];
  pa.ss = ws + WS_SS;
  pa.cnt4 = (float4*)cntI;

  prep_kernel<<<PB_TOT, 256, 0, stream>>>(pa);

  // CSR counting sort by receiver
  const int nBE = cB * cE;
  hist_kernel<<<(nBE + 255) / 256, 256, 0, stream>>>(receivers, cntI);
  scanA_kernel<<<512, 256, 0, stream>>>(cntI, bsum);
  scanB_kernel<<<1, 512, 0, stream>>>(bsum);
  scanC_kernel<<<512, 256, 0, stream>>>(cntI, bsum, pos);
  fill_kernel<<<(nBE + 255) / 256, 256, 0, stream>>>(receivers, pos, elist);

  EWb ew = { (const float*)d_in[6], (const float*)d_in[7],
             (const float*)d_in[14], (const float*)d_in[15] };   // be1, be2, bu1, bu2
  PWb pw = { (const float*)d_in[22], (const float*)d_in[23], (const float*)d_in[38],
             (const float*)d_in[39] };                            // bp1, bp2, bo1, bo2

  edge_mfma<<<dim3(cB * cEB), 256, 0, stream>>>(
      rnb, pnb, efeat, senders, receivers, elist, ew, wb,
      ws + WS_SS, ebuf);

  pnode_mfma<<<dim3(cNP / 32, cB), 256, 0, stream>>>(
      pnb, pw, wb, ws + WS_SS, (const unsigned*)ebuf, cntI, pos,
      (float*)d_out);
}

// Round 10
// 453.982 us; speedup vs baseline: 1.0123x; 1.0123x over previous
//
#include <hip/hip_runtime.h>

// ---------------- problem constants ----------------
constexpr int cB  = 2;
constexpr int cNR = 16384;
constexpr int cNP = 65536;
constexpr int cE  = 262144;
constexpr int cF  = 128;
constexpr int cEB = cE / 64;   // edge blocks per batch (4096)
constexpr int SP  = 136;   // bf16 row stride in LDS (2-way bank aliasing = free)
constexpr int EFP = 40;    // padded edge-feature row stride (K=4 -> 32 pad)

typedef unsigned short u16;
using f32x4 = __attribute__((ext_vector_type(4))) float;
using s8v   = __attribute__((ext_vector_type(8))) short;

// swizzled-weight segment bases (units of k8 = 8 K-rows; one k8 = 1024 u16)
constexpr int G8_We2 = 0, G8_Wu1 = 16, G8_Wu2 = 64, G8_Wp1 = 80, G8_Wp2 = 112, G8_Wo1 = 128;
constexpr int G8_TOT = 144;
// after main: Wo2 (K=128, N=16-padded): 256 uint4 ; We1 (K=32-padded): 512 uint4
constexpr int SWZ_N = G8_TOT * 128 + 256 + 512;      // uint4 elements (threads)
constexpr int WB_WE1 = (G8_TOT * 128 + 256) * 8;     // u16 offset of We1 block

// ws layout (float offsets)
constexpr size_t WS_CNT  = 0;
constexpr size_t WS_POS  = WS_CNT + (size_t)cB * cNP;
constexpr size_t WS_BSUM = WS_POS + (size_t)cB * cNP;
constexpr size_t WS_SS   = WS_BSUM + 512;
constexpr size_t WS_WB   = WS_SS + 3 * cB * 256;
constexpr size_t WS_RB   = WS_WB + (size_t)SWZ_N * 4;
constexpr size_t WS_PB   = WS_RB + (size_t)cB * cNR * cF / 2;
constexpr size_t WS_EL   = WS_PB + (size_t)cB * cNP * cF / 2;
constexpr size_t WS_EB   = WS_EL + (size_t)cB * cE;

// prep fusion block partition
constexpr int PB_SWZ  = (SWZ_N + 255) / 256;                       // 75
constexpr int PB_ZERO = (int)((size_t)cB * cNP * 4 / 16 / 256);    // 128
constexpr int PB_COND = 3 * cB;                                    // 6
constexpr int N2A = (int)((size_t)cB * cNR * cF / 2);              // rnode u32 pairs
constexpr int N2B = (int)((size_t)cB * cNP * cF / 2);              // pnode u32 pairs
constexpr int PB_CVT  = (N2A + N2B + 255) / 256;                   // 40960
constexpr int PB_TOT  = PB_SWZ + PB_ZERO + PB_COND + PB_CVT;

// ---------------- helpers ----------------
__device__ __forceinline__ float bf2f(u16 u) {
  union { unsigned int i; float f; } v; v.i = ((unsigned int)u) << 16; return v.f;
}
__device__ __forceinline__ u16 f2bf(float f) {        // RNE (weights only)
  union { float f; unsigned int i; } v; v.f = f;
  unsigned int x = v.i;
  return (u16)((x + 0x7fffu + ((x >> 16) & 1u)) >> 16);
}
// fast round-half-up bf16 (intermediates; 2 VALU ops)
__device__ __forceinline__ u16 f2bf_fast(float f) {
  return (u16)((__float_as_uint(f) + 0x8000u) >> 16);
}
// packed pair via v_perm_b32 (3 VALU ops total): low=bf16(a), high=bf16(b)
__device__ __forceinline__ unsigned pack2(float a, float b) {
  return __builtin_amdgcn_perm(__float_as_uint(b) + 0x8000u,
                               __float_as_uint(a) + 0x8000u, 0x07060302u);
}
// swish via single v_rcp_f32 (1-ulp)
__device__ __forceinline__ float swishf(float x) {
  return x * __builtin_amdgcn_rcpf(1.0f + __expf(-x));
}

// DPP add: x += dpp<CTRL>(x). Pure VALU (no LGKM). CTRL must be constexpr.
template <int CTRL>
__device__ __forceinline__ float dpp_add(float x) {
  int xi = __float_as_int(x);
  int r = __builtin_amdgcn_update_dpp(xi, xi, CTRL, 0xf, 0xf, false);
  return x + __int_as_float(r);
}

// direct global->LDS DMA: 4B per lane, dest = uniform base + lane*4
__device__ __forceinline__ void gload4_lds(const u16* gsrc, u16* lds) {
  __builtin_amdgcn_global_load_lds(
      (const __attribute__((address_space(1))) void*)gsrc,
      (__attribute__((address_space(3))) void*)lds, 4, 0, 0);
}

// ---- column-strip MFMA pass, M=64: wave covers rows 0..63 x 32-col strip ----
// (no setprio: r8 measured dur-null and correlated with write amplification)
__device__ __forceinline__ void kloop128s(const u16* act, const u16* __restrict__ wbg,
                                          f32x4 (&acc)[4][2], int cw, int l16, int quad) {
  s8v bf[4][2];
#pragma unroll
  for (int k0 = 0; k0 < 4; ++k0)
#pragma unroll
    for (int ci = 0; ci < 2; ++ci)
      bf[k0][ci] = *(const s8v*)(wbg + ((size_t)(k0 * 4 + quad) * 128 + cw + ci * 16 + l16) * 8);
#pragma unroll
  for (int k0 = 0; k0 < 4; ++k0) {
    s8v af[4];
#pragma unroll
    for (int ri = 0; ri < 4; ++ri)
      af[ri] = *(const s8v*)(act + (ri * 16 + l16) * SP + k0 * 32 + quad * 8);
#pragma unroll
    for (int ri = 0; ri < 4; ++ri)
#pragma unroll
      for (int ci = 0; ci < 2; ++ci)
        acc[ri][ci] = __builtin_amdgcn_mfma_f32_16x16x32_bf16(af[ri], bf[k0][ci], acc[ri][ci], 0, 0, 0);
  }
}

__device__ __forceinline__ void init_acc_s(f32x4 (&acc)[4][2], const float* __restrict__ bias,
                                           int cw, int l16) {
#pragma unroll
  for (int ci = 0; ci < 2; ++ci) {
    float bv = bias[cw + ci * 16 + l16];
#pragma unroll
    for (int ri = 0; ri < 4; ++ri) acc[ri][ci] = (f32x4){bv, bv, bv, bv};
  }
}

// conditioned LayerNorm, M=64 rows; 16-lane reduce via DPP row_ror (VALU only)
__device__ __forceinline__ void cond_norm_s(f32x4 (&acc)[4][2], float* red, float* musig,
                                            const float* __restrict__ ssp,
                                            int cw, int l16, int quad, int wv, int t) {
  __syncthreads();                 // prior LDS reads done; red/musig reuse safe
#pragma unroll
  for (int ri = 0; ri < 4; ++ri)
#pragma unroll
    for (int reg = 0; reg < 4; ++reg) {
      float v0 = acc[ri][0][reg], v1 = acc[ri][1][reg];
      float s = v0 + v1;
      float q = v0 * v0 + v1 * v1;
      s = dpp_add<0x128>(s); q = dpp_add<0x128>(q);   // row_ror:8
      s = dpp_add<0x124>(s); q = dpp_add<0x124>(q);   // row_ror:4
      s = dpp_add<0x122>(s); q = dpp_add<0x122>(q);   // row_ror:2
      s = dpp_add<0x121>(s); q = dpp_add<0x121>(q);   // row_ror:1
      if (l16 == 0) {
        int row = ri * 16 + quad * 4 + reg;
        red[row * 8 + wv * 2]     = s;
        red[row * 8 + wv * 2 + 1] = q;
      }
    }
  __syncthreads();
  if (t < 64) {
    float sum = red[t * 8 + 0] + red[t * 8 + 2] + red[t * 8 + 4] + red[t * 8 + 6];
    float sq  = red[t * 8 + 1] + red[t * 8 + 3] + red[t * 8 + 5] + red[t * 8 + 7];
    float mu  = sum * (1.0f / 128.0f);
    float var = fmaxf(sq * (1.0f / 128.0f) - mu * mu, 0.0f);
    musig[t * 2]     = mu;
    musig[t * 2 + 1] = __builtin_amdgcn_rsqf(var + 1e-6f);
  }
  __syncthreads();
  float scl[2], shf[2];
#pragma unroll
  for (int ci = 0; ci < 2; ++ci) {
    int col = cw + ci * 16 + l16;
    scl[ci] = 1.0f + ssp[col];
    shf[ci] = ssp[128 + col];
  }
#pragma unroll
  for (int ri = 0; ri < 4; ++ri)
#pragma unroll
    for (int reg = 0; reg < 4; ++reg) {
      int row = ri * 16 + quad * 4 + reg;
      float mu = musig[row * 2], is = musig[row * 2 + 1];
#pragma unroll
      for (int ci = 0; ci < 2; ++ci)
        acc[ri][ci][reg] = (acc[ri][ci][reg] - mu) * is * scl[ci] + shf[ci];
    }
}

template <bool DOSWISH>
__device__ __forceinline__ void store_s(u16* buf, const f32x4 (&acc)[4][2],
                                        int cw, int l16, int quad) {
#pragma unroll
  for (int ri = 0; ri < 4; ++ri)
#pragma unroll
    for (int reg = 0; reg < 4; ++reg) {
      int row = ri * 16 + quad * 4 + reg;
#pragma unroll
      for (int ci = 0; ci < 2; ++ci) {
        float v = acc[ri][ci][reg];
        if (DOSWISH) v = swishf(v);
        buf[row * SP + cw + ci * 16 + l16] = f2bf_fast(v);
      }
    }
}

// ---------------- fused prep kernel: swz | zero(cntI) | cond | cvt ----------------
struct SwzSrc { const float* p[7]; };  // We2, Wu1, Wu2, Wp1, Wp2, Wo1, We1

struct PrepArgs {
  SwzSrc sw; const float* Wo2; u16* wb;
  const float* rnode; u16* rnb;
  const float* pnode; u16* pnb;
  const float* tau;
  const float* C1[3]; const float* c1v[3]; const float* C2[3]; const float* c2v[3];
  float* ss;
  float4* cnt4;
};

__device__ void swz_one(int t, const SwzSrc& s, const float* __restrict__ Wo2,
                        u16* __restrict__ wb) {
  if (t >= SWZ_N) return;
  if (t >= G8_TOT * 128 + 256) {          // We1: K=4 zero-padded to 32
    int idx3 = t - (G8_TOT * 128 + 256);
    int k8 = idx3 >> 7, n = idx3 & 127;
    const float* We1 = s.p[6];
    u16 v[8];
#pragma unroll
    for (int j = 0; j < 8; ++j) {
      int k = k8 * 8 + j;
      v[j] = (k < 4) ? f2bf(We1[(size_t)k * 128 + n]) : (u16)0;
    }
    ((uint4*)wb)[t] = *(uint4*)v;
    return;
  }
  if (t >= G8_TOT * 128) {                // Wo2 tail
    int idx2 = t - G8_TOT * 128;
    int k8 = idx2 >> 4, n = idx2 & 15;
    u16 v[8];
#pragma unroll
    for (int j = 0; j < 8; ++j)
      v[j] = (n < 4) ? f2bf(Wo2[(size_t)(k8 * 8 + j) * 4 + n]) : (u16)0;
    ((uint4*)wb)[G8_TOT * 128 + k8 * 16 + n] = *(uint4*)v;
    return;
  }
  int n = t & 127, g8 = t >> 7;
  int seg, base;
  if (g8 < G8_Wu1)      { seg = 0; base = G8_We2; }
  else if (g8 < G8_Wu2) { seg = 1; base = G8_Wu1; }
  else if (g8 < G8_Wp1) { seg = 2; base = G8_Wu2; }
  else if (g8 < G8_Wp2) { seg = 3; base = G8_Wp1; }
  else if (g8 < G8_Wo1) { seg = 4; base = G8_Wp2; }
  else                  { seg = 5; base = G8_Wo1; }
  const float* W = s.p[seg];
  int k8l = g8 - base;
  u16 v[8];
#pragma unroll
  for (int j = 0; j < 8; ++j) {
    int kd = k8l * 8 + j;
    int ks = kd;
    if (seg == 3 && kd >= 128) {          // Wp1 mean half: inverse col-interleave
      int p = kd - 128;
      ks = 128 + ((p >> 5) << 5) + ((p & 1) << 4) + ((p & 31) >> 1);
    }
    v[j] = f2bf(W[(size_t)ks * 128 + n]);
  }
  ((uint4*)wb)[g8 * 128 + n] = *(uint4*)v;
}

__global__ void prep_kernel(PrepArgs a) {
  int blk = blockIdx.x, tid = threadIdx.x;
  if (blk < PB_SWZ) {
    swz_one(blk * 256 + tid, a.sw, a.Wo2, a.wb);
    return;
  }
  blk -= PB_SWZ;
  if (blk < PB_ZERO) {
    a.cnt4[blk * 256 + tid] = make_float4(0.f, 0.f, 0.f, 0.f);
    return;
  }
  blk -= PB_ZERO;
  if (blk < PB_COND) {
    int set = blk / cB, b = blk - set * cB, j = tid;
    const float* C1 = a.C1[set];  const float* c1 = a.c1v[set];
    const float* C2 = a.C2[set];  const float* c2 = a.c2v[set];
    float tf = a.tau[b];
    float acc = c2[j];
    for (int k = 0; k < 16; ++k) {
      float h = swishf(tf * C1[k] + c1[k]);
      acc = fmaf(h, C2[k * 256 + j], acc);
    }
    a.ss[(size_t)set * cB * 256 + (size_t)b * 256 + j] = acc;
    return;
  }
  blk -= PB_COND;
  int i = blk * 256 + tid;
  if (i < N2A) {
    float2 v = ((const float2*)a.rnode)[i];
    ((unsigned*)a.rnb)[i] = pack2(v.x, v.y);
  } else if (i < N2A + N2B) {
    int k = i - N2A;
    float2 v = ((const float2*)a.pnode)[k];
    ((unsigned*)a.pnb)[k] = pack2(v.x, v.y);
  }
}

// ---------------- CSR build: histogram -> scanA -> scanBC -> fill ----------------
__global__ void hist_kernel(const int* __restrict__ receivers, int* __restrict__ cntI) {
  int i = blockIdx.x * 256 + threadIdx.x;
  if (i >= cB * cE) return;
  int b = i / cE;
  int r = min(max(receivers[i], 0), cNP - 1);
  atomicAdd(&cntI[(size_t)b * cNP + r], 1);
}

__global__ void scanA_kernel(const int* __restrict__ cntI, int* __restrict__ bsum) {
  __shared__ int red[256];
  int g = blockIdx.x, t = threadIdx.x;
  red[t] = cntI[g * 256 + t];
  __syncthreads();
  for (int s = 128; s > 0; s >>= 1) {
    if (t < s) red[t] += red[t + s];
    __syncthreads();
  }
  if (t == 0) bsum[g] = red[0];
}

// merged scanB+scanC: each block recomputes its own exclusive block offset
// (sum of bsum[0..g-1], trivially cheap) then does the local 256-wide scan.
__global__ void scanBC_kernel(const int* __restrict__ cntI, const int* __restrict__ bsum,
                              int* __restrict__ pos) {
  __shared__ int s0[256], s1[256];
  int g = blockIdx.x, t = threadIdx.x;
  int v = (t < g) ? bsum[t] : 0;
  if (t + 256 < g) v += bsum[t + 256];
  s0[t] = v;
  __syncthreads();
  for (int s = 128; s > 0; s >>= 1) {
    if (t < s) s0[t] += s0[t + s];
    __syncthreads();
  }
  int boff = s0[0];
  __syncthreads();                 // all threads read boff before s0 reuse
  int v0 = cntI[g * 256 + t];
  s0[t] = v0;
  __syncthreads();
  int* src = s0; int* dst = s1;
  for (int s = 1; s < 256; s <<= 1) {
    dst[t] = src[t] + ((t >= s) ? src[t - s] : 0);
    __syncthreads();
    int* tmp = src; src = dst; dst = tmp;
  }
  pos[g * 256 + t] = src[t] - v0 + boff;   // exclusive global offset
}

__global__ void fill_kernel(const int* __restrict__ receivers, int* __restrict__ pos,
                            int* __restrict__ elist) {
  int i = blockIdx.x * 256 + threadIdx.x;
  if (i >= cB * cE) return;
  int b = i / cE, e = i - b * cE;
  int r = min(max(receivers[i], 0), cNP - 1);
  int idx = atomicAdd(&pos[(size_t)b * cNP + r], 1);
  elist[idx] = e;           // batch0 fills [0,E), batch1 [E,2E); pos ends = row ends
}

// ---------------- fused MFMA edge pipeline (r6 structure, proven best) ----------------
struct EWb { const float *be1, *be2, *bu1, *bu2; };

struct __align__(16) EdgeSmem {
  u16 bufE[64 * SP];            // e_emb (post-norm bf16; Wu1 e-operand + final residual)
  u16 bufX[64 * SP];            // h_embed -> sf -> rf -> h2
  union {
    u16 ef[64 * EFP];           // padded bf16 edge features (embed MFMA A)
    struct { float red[512]; float musig[128]; } r;
  } u;
  int sidx[64], ridx[64];
};  // 40448 B -> 4 blocks/CU

__global__ __launch_bounds__(256, 4) void edge_mfma(
    const u16* __restrict__ rnb, const u16* __restrict__ pnb,
    const float* __restrict__ efeat, const int* __restrict__ senders,
    const int* __restrict__ receivers, const int* __restrict__ elist,
    EWb w, const u16* __restrict__ wb,
    const float* __restrict__ ss, u16* __restrict__ ebuf) {
  __shared__ EdgeSmem sm;
  const int t = threadIdx.x, wv = t >> 6, lane = t & 63, l16 = lane & 15, quad = lane >> 4;
  const int cw = wv * 32;          // column strip base
  // XCD-chunked swizzle: contiguous sorted-edge chunks per XCD (L2 locality on pnb).
  const int raw = blockIdx.x;                       // 0..8191
  const int swz = (raw & 7) * (cB * cEB / 8) + (raw >> 3);
  const int b   = swz / cEB;

  // ---- stage sorted edge ids, indices, zero-padded bf16 edge features ----
  if (t < 64) {
    int eid = elist[(size_t)swz * 64 + t];          // coalesced
    size_t ge = (size_t)b * cE + eid;
    sm.sidx[t] = min(max(senders[ge], 0), cNR - 1);
    sm.ridx[t] = min(max(receivers[ge], 0), cNP - 1);
    float4 ef = *(const float4*)(efeat + ge * 4);   // random 16B gather (L2/L3 resident)
    uint4 w0 = { pack2(ef.x, ef.y), pack2(ef.z, ef.w), 0u, 0u };
    uint4 zz = { 0u, 0u, 0u, 0u };
    uint4* rowp = (uint4*)(sm.u.ef + (size_t)t * EFP);
    rowp[0] = w0; rowp[1] = zz; rowp[2] = zz; rowp[3] = zz; rowp[4] = zz;
  }
  __syncthreads();  // b1

  f32x4 acc[4][2];

  // ---- embed L1 via MFMA (K=32 zero-padded) + swish -> X ----
  init_acc_s(acc, w.be1, cw, l16);
  {
    const u16* wbe1 = wb + WB_WE1;
    s8v bf0 = *(const s8v*)(wbe1 + ((size_t)quad * 128 + cw + l16) * 8);
    s8v bf1 = *(const s8v*)(wbe1 + ((size_t)quad * 128 + cw + 16 + l16) * 8);
#pragma unroll
    for (int ri = 0; ri < 4; ++ri) {
      s8v af = *(const s8v*)(sm.u.ef + (ri * 16 + l16) * EFP + quad * 8);
      acc[ri][0] = __builtin_amdgcn_mfma_f32_16x16x32_bf16(af, bf0, acc[ri][0], 0, 0, 0);
      acc[ri][1] = __builtin_amdgcn_mfma_f32_16x16x32_bf16(af, bf1, acc[ri][1], 0, 0, 0);
    }
  }
  store_s<true>(sm.bufX, acc, cw, l16, quad);   // h_embed
  __syncthreads();  // b2

  // ---- embed L2 + cond-norm(set0) -> e_emb into bufE (LDS) ----
  init_acc_s(acc, w.be2, cw, l16);
  kloop128s(sm.bufX, wb + (size_t)G8_We2 * 1024, acc, cw, l16, quad);
  cond_norm_s(acc, sm.u.r.red, sm.u.r.musig, ss + (size_t)b * 256, cw, l16, quad, wv, t);
  store_s<false>(sm.bufE, acc, cw, l16, quad);  // e_emb

  // ---- update L1 (K=384 = sf|e|rf), sequenced through bufX ----
#pragma unroll
  for (int rr = 0; rr < 16; ++rr) {   // sf: global->LDS DMA; SALU base via readfirstlane
    int row = wv * 16 + rr;
    int si = __builtin_amdgcn_readfirstlane(sm.sidx[row]);
    gload4_lds(rnb + ((size_t)b * cNR + si) * cF + lane * 2,
               sm.bufX + row * SP);
  }
  f32x4 accU[4][2];
  init_acc_s(accU, w.bu1, cw, l16);
  __syncthreads();  // b4: sf landed; bufE(e_emb) visible to all waves
  kloop128s(sm.bufX, wb + (size_t)(G8_Wu1 + 16) * 1024, accU, cw, l16, quad);  // sf block
  __syncthreads();  // b5: sf reads done
#pragma unroll
  for (int rr = 0; rr < 16; ++rr) {   // rf: DMA from bf16 pnode (sorted -> L2-local)
    int row = wv * 16 + rr;
    int ri_ = __builtin_amdgcn_readfirstlane(sm.ridx[row]);
    gload4_lds(pnb + ((size_t)b * cNP + ri_) * cF + lane * 2,
               sm.bufX + row * SP);
  }
  // e block from bufE overlaps the rf DMA flight time
  kloop128s(sm.bufE, wb + (size_t)G8_Wu1 * 1024, accU, cw, l16, quad);         // e block
  __syncthreads();  // b6: rf landed
  kloop128s(sm.bufX, wb + (size_t)(G8_Wu1 + 32) * 1024, accU, cw, l16, quad);  // rf block
  __syncthreads();  // b7: rf reads done
  store_s<true>(sm.bufX, accU, cw, l16, quad);  // h2
  __syncthreads();  // b8

  // ---- update L2 + cond-norm(set1) ----
  init_acc_s(acc, w.bu2, cw, l16);
  kloop128s(sm.bufX, wb + (size_t)G8_Wu2 * 1024, acc, cw, l16, quad);
  cond_norm_s(acc, sm.u.r.red, sm.u.r.musig, ss + (size_t)(cB + b) * 256, cw, l16, quad, wv, t);

  // ---- e_final = e_emb + u -> DIRECT packed store to ebuf (col-interleaved) ----
  // position p = 32*wv + 2*l16 + ci holds feature f = 32*wv + 16*ci + l16;
  // compensated by the Wp1-mean K-permute in swz. No LDS round trip, no barrier.
  {
    unsigned* eb32o = (unsigned*)ebuf + (size_t)(swz * 64) * 64;
#pragma unroll
    for (int ri = 0; ri < 4; ++ri)
#pragma unroll
      for (int reg = 0; reg < 4; ++reg) {
        int row = ri * 16 + quad * 4 + reg;
        float v0 = acc[ri][0][reg] + bf2f(sm.bufE[row * SP + cw + l16]);
        float v1 = acc[ri][1][reg] + bf2f(sm.bufE[row * SP + cw + 16 + l16]);
        eb32o[(size_t)row * 64 + wv * 16 + l16] = pack2(v0, v1);
      }
  }
}

// ---------------- fused MFMA pnode pipeline (r8 M=64 structure) ----------------
struct PWb { const float *bp1, *bp2, *bo1, *bo2; };

struct __align__(16) PnodeSmem {
  u16 bufP[64 * SP];   // pf -> p_new
  u16 bufX[64 * SP];   // mean (col-interleaved; Wp1-mean K permuted) -> h1 -> h_out
  float red[512];
  float musig[128];
  float cinv[64];
  int startA[64];
  int endA[72];        // +8 sentinel for wave 3
};  // ~38.2 KB -> 4 blocks/CU

__global__ __launch_bounds__(256, 4) void pnode_mfma(
    const u16* __restrict__ pnb, PWb w, const u16* __restrict__ wb,
    const float* __restrict__ ss, const unsigned* __restrict__ eb32,
    const int* __restrict__ cntI, const int* __restrict__ pos,
    float* __restrict__ out) {
  __shared__ PnodeSmem sm;
  const int t = threadIdx.x, wv = t >> 6, lane = t & 63, l16 = lane & 15, quad = lane >> 4;
  const int cw = wv * 32;
  const int b  = blockIdx.y;
  const int n0 = blockIdx.x * 64;

  if (t < 64) {
    size_t g = (size_t)b * cNP + n0 + t;
    int c  = cntI[g];
    int e_ = pos[g];               // end offset (post-fill)
    sm.startA[t] = e_ - c;
    sm.endA[t]   = e_;
    sm.cinv[t]   = __builtin_amdgcn_rcpf(fmaxf((float)c, 1.0f));
  } else if (t < 72) {
    sm.endA[t] = 0x7fffffff;       // sentinel
  }
  __syncthreads();  // b1

  // ---- pf rows -> bufP (coalesced) ----
#pragma unroll
  for (int rr = 0; rr < 16; ++rr) {
    int row = wv * 16 + rr;
    unsigned pvu = *(const unsigned*)(pnb + (((size_t)b * cNP + n0 + row) * cF + lane * 2));
    *(unsigned*)(sm.bufP + row * SP + lane * 2) = pvu;
  }

  // ---- segment-mean: linear scan; loop state scalarized via readfirstlane ----
  {
    const int nodeLo = wv * 16;
    int cur  = nodeLo;
    int bnd  = __builtin_amdgcn_readfirstlane(sm.endA[cur]);
    int s    = __builtin_amdgcn_readfirstlane(sm.startA[nodeLo]);
    const int sEnd = __builtin_amdgcn_readfirstlane(sm.endA[nodeLo + 15]);
    float a0 = 0.f, a1 = 0.f;
    for (; s < sEnd; s += 8) {
      unsigned v[8];
      int m = sEnd - s;            // >=1
#pragma unroll
      for (int j = 0; j < 8; ++j)
        if (j < m) v[j] = eb32[(size_t)(s + j) * 64 + lane];   // 8-deep MLP, saddr form
#pragma unroll
      for (int j = 0; j < 8; ++j) {
        if (j < m) {
          while (s + j == bnd) {   // flush finished node(s); wave-uniform
            float ci = sm.cinv[cur];
            *(unsigned*)(sm.bufX + cur * SP + lane * 2) = pack2(a0 * ci, a1 * ci);
            a0 = a1 = 0.f; ++cur;
            bnd = __builtin_amdgcn_readfirstlane(sm.endA[cur]);
          }
          a0 += bf2f((u16)(v[j] & 0xffffu));
          a1 += bf2f((u16)(v[j] >> 16));
        }
      }
    }
    while (cur < nodeLo + 16) {    // flush trailing node(s)
      float ci = sm.cinv[cur];
      *(unsigned*)(sm.bufX + cur * SP + lane * 2) = pack2(a0 * ci, a1 * ci);
      a0 = a1 = 0.f; ++cur;
    }
  }
  __syncthreads();  // b2

  f32x4 acc[4][2];

  // ---- pnode L1: K=256 over [pf|mean] (mean half K-permuted in wb) ----
  init_acc_s(acc, w.bp1, cw, l16);
  kloop128s(sm.bufP, wb + (size_t)G8_Wp1 * 1024, acc, cw, l16, quad);
  kloop128s(sm.bufX, wb + (size_t)(G8_Wp1 + 16) * 1024, acc, cw, l16, quad);
  __syncthreads();  // b3: all waves done reading bufX(mean)
  store_s<true>(sm.bufX, acc, cw, l16, quad);  // h1
  __syncthreads();  // b4

  // ---- pnode L2 + cond-norm(set2) + residual -> bufP ----
  init_acc_s(acc, w.bp2, cw, l16);
  kloop128s(sm.bufX, wb + (size_t)G8_Wp2 * 1024, acc, cw, l16, quad);
  cond_norm_s(acc, sm.red, sm.musig, ss + (size_t)(2 * cB + b) * 256, cw, l16, quad, wv, t);
#pragma unroll
  for (int ri = 0; ri < 4; ++ri)
#pragma unroll
    for (int reg = 0; reg < 4; ++reg) {
      int row = ri * 16 + quad * 4 + reg;
#pragma unroll
      for (int ci = 0; ci < 2; ++ci)
        acc[ri][ci][reg] += bf2f(sm.bufP[row * SP + cw + ci * 16 + l16]);
    }
  __syncthreads();  // b5: all waves done residual-reading bufP
  store_s<false>(sm.bufP, acc, cw, l16, quad);  // p_new
  __syncthreads();  // b6

  // ---- output L1: K=128 -> bufX ----
  init_acc_s(acc, w.bo1, cw, l16);
  kloop128s(sm.bufP, wb + (size_t)G8_Wo1 * 1024, acc, cw, l16, quad);
  store_s<true>(sm.bufX, acc, cw, l16, quad);
  __syncthreads();  // b7

  // ---- output L2 via MFMA: K=128, N=16 (4 used) ----
  {
    const u16* wo2 = wb + (size_t)G8_TOT * 1024;
    float bv = (l16 < 4) ? w.bo2[l16] : 0.0f;
    f32x4 a1 = {bv, bv, bv, bv};
#pragma unroll
    for (int k0 = 0; k0 < 4; ++k0) {
      s8v af = *(const s8v*)(sm.bufX + (wv * 16 + l16) * SP + k0 * 32 + quad * 8);
      s8v bf = *(const s8v*)(wo2 + ((size_t)(k0 * 4 + quad) * 16 + l16) * 8);
      a1 = __builtin_amdgcn_mfma_f32_16x16x32_bf16(af, bf, a1, 0, 0, 0);
    }
    if (l16 < 4) {
      size_t obase = (size_t)b * cNP + n0 + wv * 16 + quad * 4;
#pragma unroll
      for (int reg = 0; reg < 4; ++reg)
        out[(obase + reg) * 4 + l16] = a1[reg];
    }
  }
}

// ---------------- launch ----------------
extern "C" void kernel_launch(void* const* d_in, const int* in_sizes, int n_in,
                              void* d_out, int out_size, void* d_ws, size_t ws_size,
                              hipStream_t stream) {
  const float* rnode = (const float*)d_in[0];
  const float* pnode = (const float*)d_in[1];
  const float* efeat = (const float*)d_in[2];
  const float* tau   = (const float*)d_in[3];
  const int* senders   = (const int*)d_in[40];
  const int* receivers = (const int*)d_in[41];
  float* ws = (float*)d_ws;
  int* cntI  = (int*)(ws + WS_CNT);
  int* pos   = (int*)(ws + WS_POS);
  int* bsum  = (int*)(ws + WS_BSUM);
  u16* wb    = (u16*)(ws + WS_WB);
  u16* rnb   = (u16*)(ws + WS_RB);         // bf16 rnode copy
  u16* pnb   = (u16*)(ws + WS_PB);         // bf16 pnode copy
  int* elist = (int*)(ws + WS_EL);         // receiver-sorted edge ids [B*E]
  u16* ebuf  = (u16*)(ws + WS_EB);         // sorted edge latents [B*E][128]

  PrepArgs pa;
  pa.sw.p[0] = (const float*)d_in[5];   // We2
  pa.sw.p[1] = (const float*)d_in[12];  // Wu1
  pa.sw.p[2] = (const float*)d_in[13];  // Wu2
  pa.sw.p[3] = (const float*)d_in[20];  // Wp1
  pa.sw.p[4] = (const float*)d_in[21];  // Wp2
  pa.sw.p[5] = (const float*)d_in[36];  // Wo1
  pa.sw.p[6] = (const float*)d_in[4];   // We1 (K=4 -> 32 padded)
  pa.Wo2 = (const float*)d_in[37];
  pa.wb = wb;
  pa.rnode = rnode; pa.rnb = rnb;
  pa.pnode = pnode; pa.pnb = pnb;
  pa.tau = tau;
  pa.C1[0] = (const float*)d_in[8];   pa.c1v[0] = (const float*)d_in[10];
  pa.C2[0] = (const float*)d_in[9];   pa.c2v[0] = (const float*)d_in[11];
  pa.C1[1] = (const float*)d_in[16];  pa.c1v[1] = (const float*)d_in[18];
  pa.C2[1] = (const float*)d_in[17];  pa.c2v[1] = (const float*)d_in[19];
  pa.C1[2] = (const float*)d_in[24];  pa.c1v[2] = (const float*)d_in[26];
  pa.C2[2] = (const float*)d_in[25];  pa.c2v[2] = (const float*)d_in[27];
  pa.ss = ws + WS_SS;
  pa.cnt4 = (float4*)cntI;

  prep_kernel<<<PB_TOT, 256, 0, stream>>>(pa);

  // CSR counting sort by receiver (scanB folded into scanC)
  const int nBE = cB * cE;
  hist_kernel<<<(nBE + 255) / 256, 256, 0, stream>>>(receivers, cntI);
  scanA_kernel<<<512, 256, 0, stream>>>(cntI, bsum);
  scanBC_kernel<<<512, 256, 0, stream>>>(cntI, bsum, pos);
  fill_kernel<<<(nBE + 255) / 256, 256, 0, stream>>>(receivers, pos, elist);

  EWb ew = { (const float*)d_in[6], (const float*)d_in[7],
             (const float*)d_in[14], (const float*)d_in[15] };   // be1, be2, bu1, bu2
  PWb pw = { (const float*)d_in[22], (const float*)d_in[23], (const float*)d_in[38],
             (const float*)d_in[39] };                            // bp1, bp2, bo1, bo2

  edge_mfma<<<dim3(cB * cEB), 256, 0, stream>>>(
      rnb, pnb, efeat, senders, receivers, elist, ew, wb,
      ws + WS_SS, ebuf);

  pnode_mfma<<<dim3(cNP / 64, cB), 256, 0, stream>>>(
      pnb, pw, wb, ws + WS_SS, (const unsigned*)ebuf, cntI, pos,
      (float*)d_out);
}